// Round 2
// baseline (2668.006 us; speedup 1.0000x reference)
//
#include <hip/hip_runtime.h>
#include <hip/hip_fp16.h>

typedef __half f16;

#define NN 255        // nodes
#define NNP 256       // padded DAD row stride
#define BB 512        // batch
#define MROWS (BB * NN)   // 130560

static __device__ __forceinline__ float ldf(float x) { return x; }
static __device__ __forceinline__ float ldf(f16 x) { return __half2float(x); }
static __device__ __forceinline__ void stf(float* p, float v) { *p = v; }
static __device__ __forceinline__ void stf(f16* p, float v) { *p = __float2half(v); }

// ---------------- DAD build ----------------

__global__ void zero_k(float* p, int n) {
    int i = blockIdx.x * 256 + threadIdx.x;
    if (i < n) p[i] = 0.f;
}

__global__ void scatter_k(const int* __restrict__ idx, const float* __restrict__ vals,
                          float* __restrict__ dad, int nnz) {
    int t = blockIdx.x * 256 + threadIdx.x;
    if (t < nnz) {
        int i = idx[2 * t];
        int k = idx[2 * t + 1];
        atomicAdd(&dad[i * NNP + k], vals[t]);
    }
}

__global__ void rowsum_k(const float* __restrict__ dad, float* __restrict__ r) {
    int i = blockIdx.x * 64 + threadIdx.x;
    if (i < NN) {
        float s = 0.f;
        for (int k = 0; k < NN; k++) s += dad[i * NNP + k];
        r[i] = s;
    }
}

// ---------------- L0 dense (K=2 rank-2 expansion): C = relu(A@W + r*b) ----------------
__global__ __launch_bounds__(256) void expand2_k(const f16* __restrict__ A,
                                                 const float* __restrict__ W,
                                                 const float* __restrict__ bias,
                                                 const float* __restrict__ rvec,
                                                 f16* __restrict__ C) {
    int i = blockIdx.x * 256 + threadIdx.x;   // over MROWS*400
    if (i >= MROWS * 400) return;
    int m = i / 400;
    int n = i - m * 400;
    float a0 = ldf(A[2 * m]), a1 = ldf(A[2 * m + 1]);
    float v = a0 * W[n] + a1 * W[400 + n] + rvec[m % NN] * bias[n];
    C[i] = __float2half(fmaxf(v, 0.f));
}

// ---------------- generic dense GEMM: C[M,N] = epi(A[M,K] @ W[K,N]) ----------------
// MODE 1: C = A@W + bias                 (feeds a DAD-after multiply)
// MODE 2: C = relu(A@W + r[m%255]*bias)  (follows a DAD-first multiply)
template <int MODE>
__global__ __launch_bounds__(256) void dense_gemm(const f16* __restrict__ A,
                                                  const float* __restrict__ W,
                                                  const float* __restrict__ bias,
                                                  const float* __restrict__ rvec,
                                                  f16* __restrict__ C,
                                                  int M, int K, int N) {
    __shared__ float As[16][128];
    __shared__ float Bs[16][132];

    const int tid = threadIdx.x;
    const int m0 = blockIdx.x * 128;
    const int n0 = blockIdx.y * 128;
    const int tx = tid & 15;
    const int ty = tid >> 4;

    float acc[8][8];
#pragma unroll
    for (int i = 0; i < 8; i++)
#pragma unroll
        for (int j = 0; j < 8; j++) acc[i][j] = 0.f;

    const int row0 = ty * 4, row1 = 64 + ty * 4;
    const int col0 = tx * 4, col1 = 64 + tx * 4;

    const int am = tid >> 1;          // A tile row (0..127)
    const int ak = (tid & 1) * 8;     // A tile k start (0 or 8)
    const int bk = tid >> 4;          // B tile k (0..15)
    const int bn = (tid & 15) * 8;    // B tile n start

    for (int k0 = 0; k0 < K; k0 += 16) {
        {
            int gm = m0 + am;
            const f16* ap = A + (size_t)gm * K + k0 + ak;
#pragma unroll
            for (int j = 0; j < 8; j++) {
                int gk = k0 + ak + j;
                float v = (gm < M && gk < K) ? ldf(ap[j]) : 0.f;
                As[ak + j][am] = v;
            }
        }
        {
            int gk = k0 + bk;
            const float* wp = W + (size_t)gk * N + n0 + bn;
#pragma unroll
            for (int j = 0; j < 8; j++) {
                int gn = n0 + bn + j;
                float v = (gk < K && gn < N) ? wp[j] : 0.f;
                Bs[bk][bn + j] = v;
            }
        }
        __syncthreads();
#pragma unroll
        for (int k = 0; k < 16; k++) {
            float a[8], b[8];
#pragma unroll
            for (int i = 0; i < 4; i++) { a[i] = As[k][row0 + i]; a[4 + i] = As[k][row1 + i]; }
#pragma unroll
            for (int j = 0; j < 4; j++) { b[j] = Bs[k][col0 + j]; b[4 + j] = Bs[k][col1 + j]; }
#pragma unroll
            for (int i = 0; i < 8; i++)
#pragma unroll
                for (int j = 0; j < 8; j++) acc[i][j] += a[i] * b[j];
        }
        __syncthreads();
    }

#pragma unroll
    for (int ih = 0; ih < 2; ih++) {
#pragma unroll
        for (int i = 0; i < 4; i++) {
            int m = m0 + (ih ? row1 : row0) + i;
            if (m >= M) continue;
            float rb = (MODE == 2) ? rvec[m % NN] : 0.f;
#pragma unroll
            for (int jh = 0; jh < 2; jh++) {
#pragma unroll
                for (int j = 0; j < 4; j++) {
                    int n = n0 + (jh ? col1 : col0) + j;
                    if (n >= N) continue;
                    float v = acc[ih * 4 + i][jh * 4 + j];
                    if (MODE == 1) v += bias[n];
                    if (MODE == 2) { v += rb * bias[n]; v = fmaxf(v, 0.f); }
                    stf(&C[(size_t)m * N + n], v);
                }
            }
        }
    }
}

// ---------------- batched DAD multiply: C[b] = epi(DAD @ Y[b]) ----------------
// MODE 0: identity (DAD-first), MODE 1: relu (DAD-after; bias already folded into Y)
template <int MODE>
__global__ __launch_bounds__(256) void dad_gemm(const float* __restrict__ dad,
                                                const f16* __restrict__ Y,
                                                f16* __restrict__ C, int N) {
    __shared__ float As[16][128];
    __shared__ float Bs[16][132];

    const int b = blockIdx.z;
    const int tid = threadIdx.x;
    const int m0 = blockIdx.x * 128;
    const int n0 = blockIdx.y * 128;
    const int tx = tid & 15;
    const int ty = tid >> 4;

    float acc[8][8];
#pragma unroll
    for (int i = 0; i < 8; i++)
#pragma unroll
        for (int j = 0; j < 8; j++) acc[i][j] = 0.f;

    const int row0 = ty * 4, row1 = 64 + ty * 4;
    const int col0 = tx * 4, col1 = 64 + tx * 4;

    const int am = tid >> 1;
    const int ak = (tid & 1) * 8;
    const int bk = tid >> 4;
    const int bn = (tid & 15) * 8;

    for (int k0 = 0; k0 < NN; k0 += 16) {
        {
            int gm = m0 + am;
            const float* ap = dad + (size_t)gm * NNP + k0 + ak;
#pragma unroll
            for (int j = 0; j < 8; j++) {
                int gk = k0 + ak + j;
                float v = (gm < NN && gk < NN) ? ap[j] : 0.f;
                As[ak + j][am] = v;
            }
        }
        {
            int gk = k0 + bk;
            const f16* yp = Y + ((size_t)b * NN + gk) * N + n0 + bn;
#pragma unroll
            for (int j = 0; j < 8; j++) {
                int gn = n0 + bn + j;
                float v = (gk < NN && gn < N) ? ldf(yp[j]) : 0.f;
                Bs[bk][bn + j] = v;
            }
        }
        __syncthreads();
#pragma unroll
        for (int k = 0; k < 16; k++) {
            float a[8], bq[8];
#pragma unroll
            for (int i = 0; i < 4; i++) { a[i] = As[k][row0 + i]; a[4 + i] = As[k][row1 + i]; }
#pragma unroll
            for (int j = 0; j < 4; j++) { bq[j] = Bs[k][col0 + j]; bq[4 + j] = Bs[k][col1 + j]; }
#pragma unroll
            for (int i = 0; i < 8; i++)
#pragma unroll
                for (int j = 0; j < 8; j++) acc[i][j] += a[i] * bq[j];
        }
        __syncthreads();
    }

#pragma unroll
    for (int ih = 0; ih < 2; ih++) {
#pragma unroll
        for (int i = 0; i < 4; i++) {
            int m = m0 + (ih ? row1 : row0) + i;
            if (m >= NN) continue;
#pragma unroll
            for (int jh = 0; jh < 2; jh++) {
#pragma unroll
                for (int j = 0; j < 4; j++) {
                    int n = n0 + (jh ? col1 : col0) + j;
                    if (n >= N) continue;
                    float v = acc[ih * 4 + i][jh * 4 + j];
                    if (MODE == 1) v = fmaxf(v, 0.f);
                    stf(&C[((size_t)b * NN + m) * N + n], v);
                }
            }
        }
    }
}

// ---------------- small-N special kernels (output width 2) ----------------

// C[m,0:2] = A[m,:]@W[:,0:2] + bias   (one wave per row, K-split across lanes)
__global__ __launch_bounds__(256) void dense_n2(const f16* __restrict__ A,
                                                const float* __restrict__ W,
                                                const float* __restrict__ bias,
                                                f16* __restrict__ C, int M, int K) {
    int gw = (blockIdx.x * blockDim.x + threadIdx.x) >> 6;
    int lane = threadIdx.x & 63;
    if (gw >= M) return;
    const f16* arow = A + (size_t)gw * K;
    float a0 = 0.f, a1 = 0.f;
    for (int k = lane; k < K; k += 64) {
        float a = ldf(arow[k]);
        a0 += a * W[2 * k];
        a1 += a * W[2 * k + 1];
    }
#pragma unroll
    for (int off = 32; off > 0; off >>= 1) {
        a0 += __shfl_down(a0, off);
        a1 += __shfl_down(a1, off);
    }
    if (lane == 0) {
        stf(&C[(size_t)gw * 2 + 0], a0 + bias[0]);
        stf(&C[(size_t)gw * 2 + 1], a1 + bias[1]);
    }
}

// C[b,i,0:2] = epi(sum_k dad[i,k] * Y[b,k,0:2]); one wave per (b,i)
template <typename TI, typename TO>
__global__ __launch_bounds__(256) void dad_n2(const float* __restrict__ dad,
                                              const TI* __restrict__ Y,
                                              TO* __restrict__ C, int do_relu) {
    int gw = (blockIdx.x * blockDim.x + threadIdx.x) >> 6;
    int lane = threadIdx.x & 63;
    if (gw >= MROWS) return;
    int b = gw / NN;
    int i = gw - b * NN;
    const float* drow = dad + (size_t)i * NNP;
    const TI* yb = Y + (size_t)b * NN * 2;
    float a0 = 0.f, a1 = 0.f;
    for (int k = lane; k < NN; k += 64) {
        float d = drow[k];
        a0 += d * ldf(yb[2 * k]);
        a1 += d * ldf(yb[2 * k + 1]);
    }
#pragma unroll
    for (int off = 32; off > 0; off >>= 1) {
        a0 += __shfl_down(a0, off);
        a1 += __shfl_down(a1, off);
    }
    if (lane == 0) {
        if (do_relu) { a0 = fmaxf(a0, 0.f); a1 = fmaxf(a1, 0.f); }
        stf(&C[(size_t)gw * 2 + 0], a0);
        stf(&C[(size_t)gw * 2 + 1], a1);
    }
}

// ---------------- launcher ----------------

extern "C" void kernel_launch(void* const* d_in, const int* in_sizes, int n_in,
                              void* d_out, int out_size, void* d_ws, size_t ws_size,
                              hipStream_t stream) {
    const float* H   = (const float*)d_in[0];
    const float* smv = (const float*)d_in[1];
    const float* spv = (const float*)d_in[2];
    const float* W[6]  = {(const float*)d_in[3], (const float*)d_in[5], (const float*)d_in[7],
                          (const float*)d_in[9], (const float*)d_in[11], (const float*)d_in[13]};
    const float* Bv[6] = {(const float*)d_in[4], (const float*)d_in[6], (const float*)d_in[8],
                          (const float*)d_in[10], (const float*)d_in[12], (const float*)d_in[14]};
    const int* smi = (const int*)d_in[15];
    const int* spi = (const int*)d_in[16];
    float* out = (float*)d_out;

    char* ws = (char*)d_ws;
    float* dadsm = (float*)ws;                       // 255*256 f32
    float* dadsp = dadsm + NN * NNP;                 // 255*256 f32
    float* rsm   = (float*)(ws + 2 * NN * NNP * 4);  // 256 f32
    float* rsp   = rsm + 256;
    f16*   buf0  = (f16*)(ws + 524288);
    f16*   buf1  = buf0 + (size_t)MROWS * 400;       // each buffer: 130560*400 f16 = 104.4 MB

    // build DAD (both matrices contiguous -> one zero pass)
    zero_k<<<(2 * NN * NNP + 255) / 256, 256, 0, stream>>>(dadsm, 2 * NN * NNP);
    scatter_k<<<(2550 + 255) / 256, 256, 0, stream>>>(smi, smv, dadsm, 2550);
    scatter_k<<<(2550 + 255) / 256, 256, 0, stream>>>(spi, spv, dadsp, 2550);
    rowsum_k<<<4, 64, 0, stream>>>(dadsm, rsm);
    rowsum_k<<<4, 64, 0, stream>>>(dadsp, rsp);

    const int nwb = (MROWS * 64 + 255) / 256;  // blocks for wave-per-row kernels

    // L0 enc0 (2->400), DAD-first:  buf0 = DADsm@H ; buf1 = relu(buf0@W0 + r*b0)
    dad_n2<float, f16><<<nwb, 256, 0, stream>>>(dadsm, H, buf0, 0);
    expand2_k<<<(MROWS * 400 + 255) / 256, 256, 0, stream>>>(buf0, W[0], Bv[0], rsm, buf1);

    // L1 enc1 (400->300), DAD-after: buf0 = buf1@W1 + b1 ; buf1 = relu(DADsm@buf0)
    dense_gemm<1><<<dim3(1020, 3), 256, 0, stream>>>(buf1, W[1], Bv[1], nullptr, buf0, MROWS, 400, 300);
    dad_gemm<1><<<dim3(2, 3, BB), 256, 0, stream>>>(dadsm, buf0, buf1, 300);

    // L2 enc2 (300->100), DAD-after
    dense_gemm<1><<<dim3(1020, 1), 256, 0, stream>>>(buf1, W[2], Bv[2], nullptr, buf0, MROWS, 300, 100);
    dad_gemm<1><<<dim3(2, 1, BB), 256, 0, stream>>>(dadsm, buf0, buf1, 100);

    // L3 dec0 (100->300), DAD-first
    dad_gemm<0><<<dim3(2, 1, BB), 256, 0, stream>>>(dadsp, buf1, buf0, 100);
    dense_gemm<2><<<dim3(1020, 3), 256, 0, stream>>>(buf0, W[3], Bv[3], rsp, buf1, MROWS, 100, 300);

    // L4 dec1 (300->400), DAD-first
    dad_gemm<0><<<dim3(2, 3, BB), 256, 0, stream>>>(dadsp, buf1, buf0, 300);
    dense_gemm<2><<<dim3(1020, 4), 256, 0, stream>>>(buf0, W[4], Bv[4], rsp, buf1, MROWS, 300, 400);

    // L5 dec2 (400->2), DAD-after: buf0 = buf1@W5 + b5 ; out = relu(DADsp@buf0)
    dense_n2<<<nwb, 256, 0, stream>>>(buf1, W[5], Bv[5], buf0, MROWS, 400);
    dad_n2<f16, float><<<nwb, 256, 0, stream>>>(dadsp, buf0, out, 1);
}

// Round 3
// 759.268 us; speedup vs baseline: 3.5139x; 3.5139x over previous
//
#include <hip/hip_runtime.h>
#include <hip/hip_fp16.h>

typedef __half f16;
typedef _Float16 h8 __attribute__((ext_vector_type(8)));
typedef float f32x4 __attribute__((ext_vector_type(4)));

#define NN 255          // real nodes
#define BB 512          // batch
#define M2 131072       // 512 * 256 node-padded rows
#define LDSS 40         // LDS tile row stride in f16 (80 B: 16B-aligned, 2-way-free banks)

static __device__ __forceinline__ float h2f(f16 x) { return __half2float(x); }
static __device__ __forceinline__ f16 f2h(float x) { return __float2half(x); }

// ---------------- DAD build (f32 scatter, tiny) ----------------

__global__ void zero_k(float* p, int n) {
    int i = blockIdx.x * 256 + threadIdx.x;
    if (i < n) p[i] = 0.f;
}

__global__ void scatter_k(const int* __restrict__ idx, const float* __restrict__ vals,
                          float* __restrict__ dad, int nnz) {
    int t = blockIdx.x * 256 + threadIdx.x;
    if (t < nnz) atomicAdd(&dad[idx[2 * t] * 256 + idx[2 * t + 1]], vals[t]);
}

__global__ void rowsum_k(const float* __restrict__ dad, float* __restrict__ r) {
    int i = blockIdx.x * 64 + threadIdx.x;
    if (i < NN) {
        float s = 0.f;
        for (int k = 0; k < NN; k++) s += dad[i * 256 + k];
        r[i] = s;
    }
}

// dadh[256][256] f16 from dadf[255][256] f32; row 255 = 0
__global__ void convert_dad(const float* __restrict__ dadf, f16* __restrict__ dadh) {
    int i = blockIdx.x * 256 + threadIdx.x;   // over 2*65536
    int which = i >> 16, rc = i & 65535;
    int row = rc >> 8;
    float v = (row < NN) ? dadf[(size_t)which * NN * 256 + rc] : 0.f;
    dadh[(size_t)which * 65536 + rc] = f2h(v);
}

// Wt[n][k] = W[k][n], zero-padded to [Nfull][Kpad]
__global__ void convert_wt(const float* __restrict__ W, f16* __restrict__ Wt,
                           int K, int N, int Kpad) {
    int n = blockIdx.x;
    for (int k = threadIdx.x; k < Kpad; k += 256) {
        float v = (n < N && k < K) ? W[(size_t)k * N + n] : 0.f;
        Wt[(size_t)n * Kpad + k] = f2h(v);
    }
}

// ---------------- dense MFMA: Ct[b][n][node] = X @ W + bias (transposed out) ----------------
// A-op = Wt[n][k] (row-major), B-op = X[m][k] (row-major). D: row=n, col=m.
__global__ __launch_bounds__(256) void dense_mfma(
        const f16* __restrict__ Wt, const f16* __restrict__ X,
        const float* __restrict__ bias, f16* __restrict__ Ct,
        int Kpad, int xstride, int N) {
    __shared__ _Float16 As[128 * LDSS];
    __shared__ _Float16 Bs[128 * LDSS];
    const int tid = threadIdx.x;
    const int n0 = blockIdx.x * 128;
    const int m0 = blockIdx.y * 128;
    const int w = tid >> 6, l = tid & 63;
    const int noff = (w & 1) * 64, moff = (w >> 1) * 64;
    const int q = l >> 4, ln = l & 15;

    f32x4 acc[4][4];
#pragma unroll
    for (int i = 0; i < 4; i++)
#pragma unroll
        for (int j = 0; j < 4; j++) acc[i][j] = (f32x4){0.f, 0.f, 0.f, 0.f};

    const int r = tid >> 1, hh = tid & 1;
    const f16* gA = Wt + (size_t)(n0 + r) * Kpad + hh * 16;
    const f16* gB = X + (size_t)(m0 + r) * xstride + hh * 16;
    _Float16* lA = As + r * LDSS + hh * 16;
    _Float16* lB = Bs + r * LDSS + hh * 16;
    const _Float16* rA = As + (noff + ln) * LDSS + q * 8;
    const _Float16* rB = Bs + (moff + ln) * LDSS + q * 8;

    for (int k0 = 0; k0 < Kpad; k0 += 32) {
        uint4 va0 = *(const uint4*)gA;
        uint4 va1 = *(const uint4*)(gA + 8);
        uint4 vb0 = *(const uint4*)gB;
        uint4 vb1 = *(const uint4*)(gB + 8);
        __syncthreads();
        *(uint4*)lA = va0; *(uint4*)(lA + 8) = va1;
        *(uint4*)lB = vb0; *(uint4*)(lB + 8) = vb1;
        __syncthreads();
        h8 af[4], bf[4];
#pragma unroll
        for (int i = 0; i < 4; i++) af[i] = *(const h8*)(rA + i * 16 * LDSS);
#pragma unroll
        for (int j = 0; j < 4; j++) bf[j] = *(const h8*)(rB + j * 16 * LDSS);
#pragma unroll
        for (int i = 0; i < 4; i++)
#pragma unroll
            for (int j = 0; j < 4; j++)
                acc[i][j] = __builtin_amdgcn_mfma_f32_16x16x32_f16(af[i], bf[j], acc[i][j], 0, 0, 0);
        gA += 32; gB += 32;
    }

#pragma unroll
    for (int i = 0; i < 4; i++) {
#pragma unroll
        for (int rg = 0; rg < 4; rg++) {
            int n = n0 + noff + i * 16 + q * 4 + rg;
            if (n >= N) continue;              // Ct stored compact: width = N
            float bv = bias[n];
#pragma unroll
            for (int j = 0; j < 4; j++) {
                int m = m0 + moff + j * 16 + ln;
                int b = m >> 8, node = m & 255;
                Ct[((size_t)b * N + n) * 256 + node] = f2h(acc[i][j][rg] + bv);
            }
        }
    }
}

// ---------------- dad MFMA: X[b][node][n] = relu(DAD @ Y), Y given feature-major ----------------
// A-op = dadh[i][k] (row-major), B-op = Ct[b][n][k=node_in]. D: row=node_out, col=n.
__global__ __launch_bounds__(256) void dad_mfma(
        const f16* __restrict__ dadh, const f16* __restrict__ Ct,
        f16* __restrict__ Xout, int wc, int wx) {
    __shared__ _Float16 As[128 * LDSS];
    __shared__ _Float16 Bs[128 * LDSS];
    const int tid = threadIdx.x;
    const int i0 = blockIdx.x * 128;
    const int n0 = blockIdx.y * 128;
    const int b = blockIdx.z;
    const int w = tid >> 6, l = tid & 63;
    const int ioff = (w & 1) * 64, joff = (w >> 1) * 64;
    const int q = l >> 4, ln = l & 15;

    f32x4 acc[4][4];
#pragma unroll
    for (int i = 0; i < 4; i++)
#pragma unroll
        for (int j = 0; j < 4; j++) acc[i][j] = (f32x4){0.f, 0.f, 0.f, 0.f};

    const int r = tid >> 1, hh = tid & 1;
    const f16* gA = dadh + (size_t)(i0 + r) * 256 + hh * 16;
    // rows n0+r may exceed wc: garbage reads land in masked output cols (mapped memory follows)
    const f16* gB = Ct + ((size_t)b * wc + n0 + r) * 256 + hh * 16;
    _Float16* lA = As + r * LDSS + hh * 16;
    _Float16* lB = Bs + r * LDSS + hh * 16;
    const _Float16* rA = As + (ioff + ln) * LDSS + q * 8;
    const _Float16* rB = Bs + (joff + ln) * LDSS + q * 8;

    for (int k0 = 0; k0 < 256; k0 += 32) {
        uint4 va0 = *(const uint4*)gA;
        uint4 va1 = *(const uint4*)(gA + 8);
        uint4 vb0 = *(const uint4*)gB;
        uint4 vb1 = *(const uint4*)(gB + 8);
        __syncthreads();
        *(uint4*)lA = va0; *(uint4*)(lA + 8) = va1;
        *(uint4*)lB = vb0; *(uint4*)(lB + 8) = vb1;
        __syncthreads();
        h8 af[4], bf[4];
#pragma unroll
        for (int i = 0; i < 4; i++) af[i] = *(const h8*)(rA + i * 16 * LDSS);
#pragma unroll
        for (int j = 0; j < 4; j++) bf[j] = *(const h8*)(rB + j * 16 * LDSS);
#pragma unroll
        for (int i = 0; i < 4; i++)
#pragma unroll
            for (int j = 0; j < 4; j++)
                acc[i][j] = __builtin_amdgcn_mfma_f32_16x16x32_f16(af[i], bf[j], acc[i][j], 0, 0, 0);
        gA += 32; gB += 32;
    }

#pragma unroll
    for (int i = 0; i < 4; i++) {
#pragma unroll
        for (int rg = 0; rg < 4; rg++) {
            int node = i0 + ioff + i * 16 + q * 4 + rg;
#pragma unroll
            for (int j = 0; j < 4; j++) {
                int n = n0 + joff + j * 16 + ln;
                if (n >= wx) continue;
                float v = fmaxf(acc[i][j][rg], 0.f);
                Xout[((size_t)b * 256 + node) * wx + n] = f2h(v);
            }
        }
    }
}

// ---------------- L0: T0[b][256][2] = DADsm @ H (f32 in, f16 out, no relu) ----------------
__global__ __launch_bounds__(256) void dad2_in(const float* __restrict__ dad,
                                               const float* __restrict__ H,
                                               f16* __restrict__ T0) {
    int gw = (blockIdx.x * 256 + threadIdx.x) >> 6;
    int lane = threadIdx.x & 63;
    if (gw >= BB * NN) return;
    int b = gw / NN, i = gw - b * NN;
    const float* dr = dad + (size_t)i * 256;
    const float* yb = H + (size_t)b * NN * 2;
    float a0 = 0.f, a1 = 0.f;
    for (int k = lane; k < NN; k += 64) {
        float d = dr[k];
        a0 += d * yb[2 * k];
        a1 += d * yb[2 * k + 1];
    }
#pragma unroll
    for (int off = 32; off > 0; off >>= 1) {
        a0 += __shfl_down(a0, off);
        a1 += __shfl_down(a1, off);
    }
    if (lane == 0) {
        T0[((size_t)b * 256 + i) * 2 + 0] = f2h(a0);
        T0[((size_t)b * 256 + i) * 2 + 1] = f2h(a1);
    }
}

// ---------------- L0 expand: X0[m][400] = relu(T0 @ W0 + r[node]*b0) ----------------
__global__ __launch_bounds__(256) void expand2_k(const f16* __restrict__ T0,
                                                 const float* __restrict__ W0,
                                                 const float* __restrict__ b0,
                                                 const float* __restrict__ rsm,
                                                 f16* __restrict__ X0) {
    int m = blockIdx.x;          // over M2
    int node = m & 255;
    bool pad = (node == NN);
    float a0 = 0.f, a1 = 0.f, rv = 0.f;
    if (!pad) {
        a0 = h2f(T0[(size_t)m * 2]);
        a1 = h2f(T0[(size_t)m * 2 + 1]);
        rv = rsm[node];
    }
    for (int n = threadIdx.x; n < 400; n += 256) {
        float v = pad ? 0.f : fmaxf(a0 * W0[n] + a1 * W0[400 + n] + rv * b0[n], 0.f);
        X0[(size_t)m * 400 + n] = f2h(v);
    }
}

// ---------------- L5: T5[m][2] = X4 @ W5 + b5 ----------------
__global__ __launch_bounds__(256) void dense2(const f16* __restrict__ X4,
                                              const float* __restrict__ W5,
                                              const float* __restrict__ b5,
                                              f16* __restrict__ T5) {
    int gw = (blockIdx.x * 256 + threadIdx.x) >> 6;
    int lane = threadIdx.x & 63;
    if (gw >= M2) return;
    const f16* xr = X4 + (size_t)gw * 400;
    float a0 = 0.f, a1 = 0.f;
    for (int k = lane; k < 400; k += 64) {
        float x = h2f(xr[k]);
        a0 += x * W5[2 * k];
        a1 += x * W5[2 * k + 1];
    }
#pragma unroll
    for (int off = 32; off > 0; off >>= 1) {
        a0 += __shfl_down(a0, off);
        a1 += __shfl_down(a1, off);
    }
    if (lane == 0) {
        T5[(size_t)gw * 2 + 0] = f2h(a0 + b5[0]);
        T5[(size_t)gw * 2 + 1] = f2h(a1 + b5[1]);
    }
}

// ---------------- final: out[b][i][2] = relu(DADsp @ T5) (f32 out, unpadded) ----------------
__global__ __launch_bounds__(256) void dad2_out(const float* __restrict__ dad,
                                                const f16* __restrict__ T5,
                                                float* __restrict__ out) {
    int gw = (blockIdx.x * 256 + threadIdx.x) >> 6;
    int lane = threadIdx.x & 63;
    if (gw >= BB * NN) return;
    int b = gw / NN, i = gw - b * NN;
    const float* dr = dad + (size_t)i * 256;
    const f16* yb = T5 + (size_t)b * 512;
    float a0 = 0.f, a1 = 0.f;
    for (int k = lane; k < NN; k += 64) {
        float d = dr[k];
        a0 += d * h2f(yb[2 * k]);
        a1 += d * h2f(yb[2 * k + 1]);
    }
#pragma unroll
    for (int off = 32; off > 0; off >>= 1) {
        a0 += __shfl_down(a0, off);
        a1 += __shfl_down(a1, off);
    }
    if (lane == 0) {
        out[((size_t)b * NN + i) * 2 + 0] = fmaxf(a0, 0.f);
        out[((size_t)b * NN + i) * 2 + 1] = fmaxf(a1, 0.f);
    }
}

// ---------------- launcher ----------------

extern "C" void kernel_launch(void* const* d_in, const int* in_sizes, int n_in,
                              void* d_out, int out_size, void* d_ws, size_t ws_size,
                              hipStream_t stream) {
    const float* H   = (const float*)d_in[0];
    const float* W[6]  = {(const float*)d_in[3], (const float*)d_in[5], (const float*)d_in[7],
                          (const float*)d_in[9], (const float*)d_in[11], (const float*)d_in[13]};
    const float* Bv[6] = {(const float*)d_in[4], (const float*)d_in[6], (const float*)d_in[8],
                          (const float*)d_in[10], (const float*)d_in[12], (const float*)d_in[14]};
    const int* smi = (const int*)d_in[15];
    const int* spi = (const int*)d_in[16];
    float* out = (float*)d_out;

    char* p = (char*)d_ws;
    f16* bufA = (f16*)p;            p += 104857600;   // X buffers, max stride 400
    f16* bufB = (f16*)p;            p += 104857600;   // Ct buffers, max width 400
    float* dadsm = (float*)p;       p += 261120;      // [255][256] f32
    float* dadsp = (float*)p;       p += 261120;
    float* rsm = (float*)p;         p += 1024;
    f16* dadhsm = (f16*)p;          p += 131072;      // [256][256] f16
    f16* dadhsp = (f16*)p;          p += 131072;
    f16* Wt1 = (f16*)p;             p += 425984;      // [512][416]
    f16* Wt2 = (f16*)p;             p += 81920;       // [128][320]
    f16* Wt3 = (f16*)p;             p += 98304;       // [384][128]
    f16* Wt4 = (f16*)p;             p += 327680;      // [512][320]
    f16* T0 = (f16*)p;              p += 524288;      // [131072][2]
    f16* T5 = (f16*)p;              p += 524288;

    // ---- build DAD + weight conversion ----
    zero_k<<<510, 256, 0, stream>>>(dadsm, 2 * NN * 256);
    scatter_k<<<10, 256, 0, stream>>>(smi, (const float*)d_in[1], dadsm, 2550);
    scatter_k<<<10, 256, 0, stream>>>(spi, (const float*)d_in[2], dadsp, 2550);
    rowsum_k<<<4, 64, 0, stream>>>(dadsm, rsm);
    convert_dad<<<512, 256, 0, stream>>>(dadsm, dadhsm);
    convert_wt<<<512, 256, 0, stream>>>(W[1], Wt1, 400, 300, 416);
    convert_wt<<<128, 256, 0, stream>>>(W[2], Wt2, 300, 100, 320);
    convert_wt<<<384, 256, 0, stream>>>(W[3], Wt3, 100, 300, 128);
    convert_wt<<<512, 256, 0, stream>>>(W[4], Wt4, 300, 400, 320);

    const int nwb = (BB * NN * 64 + 255) / 256;   // 32640
    const int nwb2 = (M2 * 64) / 256;             // 32768

    // L0 enc0 (2->400), DAD-first via row-sum trick
    dad2_in<<<nwb, 256, 0, stream>>>(dadsm, H, T0);
    expand2_k<<<M2, 256, 0, stream>>>(T0, W[0], Bv[0], rsm, bufA);

    // L1 enc1 (400->300): Ct = X0@W1 + b1 ; X1 = relu(DADsm @ Ct)
    dense_mfma<<<dim3(3, 1024), 256, 0, stream>>>(Wt1, bufA, Bv[1], bufB, 416, 400, 300);
    dad_mfma<<<dim3(2, 3, BB), 256, 0, stream>>>(dadhsm, bufB, bufA, 300, 320);

    // L2 enc2 (300->100)
    dense_mfma<<<dim3(1, 1024), 256, 0, stream>>>(Wt2, bufA, Bv[2], bufB, 320, 320, 100);
    dad_mfma<<<dim3(2, 1, BB), 256, 0, stream>>>(dadhsm, bufB, bufA, 100, 128);

    // L3 dec0 (100->300), dad-after with DADsp
    dense_mfma<<<dim3(3, 1024), 256, 0, stream>>>(Wt3, bufA, Bv[3], bufB, 128, 128, 300);
    dad_mfma<<<dim3(2, 3, BB), 256, 0, stream>>>(dadhsp, bufB, bufA, 300, 320);

    // L4 dec1 (300->400)
    dense_mfma<<<dim3(4, 1024), 256, 0, stream>>>(Wt4, bufA, Bv[4], bufB, 320, 320, 400);
    dad_mfma<<<dim3(2, 4, BB), 256, 0, stream>>>(dadhsp, bufB, bufA, 400, 400);

    // L5 dec2 (400->2): T5 = X4@W5 + b5 ; out = relu(DADsp @ T5)
    dense2<<<nwb2, 256, 0, stream>>>(bufA, W[5], Bv[5], T5);
    dad2_out<<<nwb, 256, 0, stream>>>(dadsp, T5, out);
}